// Round 14
// baseline (920.149 us; speedup 1.0000x reference)
//
#include <hip/hip_runtime.h>
#include <hip/hip_bf16.h>

// ---------------------------------------------------------------------------
// TransformerBlock: LN1 -> fused QKV GEMM (V written pre-transposed) ->
//   flash causal MHA -> Wo GEMM (+x) -> LN2 -> FF1 (+b1, GELU) -> FF2 (+x2)
// B=2, T=2048, D=1024, H=16, K=64, DFF=4096. fp32 I/O, bf16 MFMA internally.
// LESSONS (R4): register arrays only in fully-unrolled loops; stage via LDS.
// LESSON (R5/R6/R8/R11): more MFMA per barrier pair wins while VGPR fits.
// LESSON (R7): watch occupancy; big acc tiles need __launch_bounds__(.,2).
// LESSON (R10): XCD block-order swizzle = 0 byte FETCH change.
// LESSON (R12): attn was barrier-convoy bound -> ping-pong K/V LDS buffers.
// LESSON (R13): SQ_LDS_BANK_CONFLICT is structural for ds_read_b128 (exactly
// 4/read, swizzle-invariant); gemm_bt is LDS-READ-THROUGHPUT bound ->
// R14: 128x256 tile / 64x128 per wave rebalances reads:MFMA to 1:1.
// ---------------------------------------------------------------------------

#define BT   4096   // B*T rows
#define DIM  1024
#define DFF  4096
#define TSEQ 2048
#define NHEAD 16
#define HDIM 64
#define QK_LD 2048   // fused Q|K buffer row width

typedef __attribute__((ext_vector_type(8))) short  bf16x8;
typedef __attribute__((ext_vector_type(4))) float  floatx4;
struct alignas(8) bf4 { __hip_bfloat16 x[4]; };

__device__ __forceinline__ void async_copy16(const __hip_bfloat16* g, __hip_bfloat16* l) {
    __builtin_amdgcn_global_load_lds(
        (const __attribute__((address_space(1))) void*)g,
        (__attribute__((address_space(3))) void*)l, 16, 0, 0);
}

__device__ __forceinline__ floatx4 mfma_bf16(bf16x8 a, bf16x8 b, floatx4 c) {
    return __builtin_amdgcn_mfma_f32_16x16x32_bf16(a, b, c, 0, 0, 0);
}

// ---------------------------------------------------------------------------
// LayerNorm: fp32 in -> bf16 out.  One block (256 thr) per row of 1024.
// ---------------------------------------------------------------------------
__device__ __forceinline__ void ln_body(const float* __restrict__ x,
                                        const float* __restrict__ g,
                                        const float* __restrict__ be,
                                        __hip_bfloat16* __restrict__ out,
                                        int row, float* red) {
    const int t = threadIdx.x;
    const float4 v = ((const float4*)(x + (size_t)row * DIM))[t];
    float s  = v.x + v.y + v.z + v.w;
    float ss = v.x * v.x + v.y * v.y + v.z * v.z + v.w * v.w;
    for (int d = 1; d < 64; d <<= 1) { s += __shfl_xor(s, d); ss += __shfl_xor(ss, d); }
    const int w = t >> 6;
    if ((t & 63) == 0) { red[w] = s; red[w + 4] = ss; }
    __syncthreads();
    s  = red[0] + red[1] + red[2] + red[3];
    ss = red[4] + red[5] + red[6] + red[7];
    const float mu = s * (1.0f / DIM);
    const float rstd = rsqrtf(ss * (1.0f / DIM) - mu * mu + 1e-5f);
    const float4 gv = ((const float4*)g)[t];
    const float4 bv = ((const float4*)be)[t];
    __hip_bfloat16* o = out + (size_t)row * DIM + t * 4;
    o[0] = __float2bfloat16((v.x - mu) * rstd * gv.x + bv.x);
    o[1] = __float2bfloat16((v.y - mu) * rstd * gv.y + bv.y);
    o[2] = __float2bfloat16((v.z - mu) * rstd * gv.z + bv.z);
    o[3] = __float2bfloat16((v.w - mu) * rstd * gv.w + bv.w);
}

__global__ __launch_bounds__(256) void ln_kernel(const float* __restrict__ x,
                                                 const float* __restrict__ g,
                                                 const float* __restrict__ be,
                                                 __hip_bfloat16* __restrict__ out) {
    __shared__ float red[8];
    ln_body(x, g, be, out, blockIdx.x, red);
}

// ---------------------------------------------------------------------------
// 64x64-tile transpose+cast body: dst[c][r] = (bf16)src[r][c]
// ---------------------------------------------------------------------------
__device__ __forceinline__ void tc_body(const float* __restrict__ src, int src_ld,
                                        __hip_bfloat16* __restrict__ dst, int dst_ld,
                                        int bx, int by, float* tile /*64*65*/) {
    const int r0 = bx * 64, c0 = by * 64;
    const int tr = threadIdx.x >> 6;   // 0..3
    const int tc = threadIdx.x & 63;   // 0..63
    for (int i = 0; i < 16; ++i) {
        const int r = i * 4 + tr;
        tile[r * 65 + tc] = src[(size_t)(r0 + r) * src_ld + c0 + tc];
    }
    __syncthreads();
    for (int i = 0; i < 16; ++i) {
        const int c = i * 4 + tr;
        dst[(size_t)(c0 + c) * dst_ld + r0 + tc] = __float2bfloat16(tile[tc * 65 + c]);
    }
}

// ---------------------------------------------------------------------------
// Fused prep: LN1 (4096 blocks) + transpose_qkv (768) + Wo^T (256) +
// W1^T (1024) + W2^T (1024) in one dispatch.  Grid = 7168.
// ---------------------------------------------------------------------------
__global__ __launch_bounds__(256) void prep_kernel(const float* __restrict__ x,
                                                   const float* __restrict__ g1,
                                                   const float* __restrict__ be1,
                                                   const float* __restrict__ Wq,
                                                   const float* __restrict__ Wk,
                                                   const float* __restrict__ Wv,
                                                   const float* __restrict__ Wo,
                                                   const float* __restrict__ W1,
                                                   const float* __restrict__ W2,
                                                   __hip_bfloat16* __restrict__ h1,
                                                   __hip_bfloat16* __restrict__ WqkvT,
                                                   __hip_bfloat16* __restrict__ WoT,
                                                   __hip_bfloat16* __restrict__ W1T,
                                                   __hip_bfloat16* __restrict__ W2T) {
    __shared__ __align__(16) float smemf[64 * 65];
    const int id = blockIdx.x;
    if (id < 4096) {
        ln_body(x, g1, be1, h1, id, smemf);
    } else if (id < 4096 + 768) {
        // transpose_qkv: Wq/Wk/Wv [H][D][64] -> WqkvT [3072][1024]
        const int i = id - 4096;
        const int bx = i & 15, hz = i >> 4;
        const int proj = hz >> 4, h = hz & 15;
        const float* W = (proj == 0 ? Wq : (proj == 1 ? Wk : Wv)) + (size_t)h * DIM * HDIM;
        const int r0 = bx * 64;
        const int tr = threadIdx.x >> 6, tc = threadIdx.x & 63;
        for (int i2 = 0; i2 < 16; ++i2) {
            const int r = i2 * 4 + tr;
            smemf[r * 65 + tc] = W[(size_t)(r0 + r) * HDIM + tc];
        }
        __syncthreads();
        for (int i2 = 0; i2 < 16; ++i2) {
            const int k = i2 * 4 + tr;
            WqkvT[(size_t)(proj * 1024 + h * 64 + k) * DIM + r0 + tc] =
                __float2bfloat16(smemf[tc * 65 + k]);
        }
    } else if (id < 4096 + 768 + 256) {
        const int i = id - (4096 + 768);
        tc_body(Wo, 1024, WoT, 1024, i & 15, i >> 4, smemf);
    } else if (id < 4096 + 768 + 256 + 1024) {
        const int i = id - (4096 + 768 + 256);
        tc_body(W1, 4096, W1T, 1024, i & 15, i >> 4, smemf);
    } else {
        const int i = id - (4096 + 768 + 256 + 1024);
        tc_body(W2, 1024, W2T, 4096, i & 63, i >> 6, smemf);
    }
}

// ---------------------------------------------------------------------------
// bf16 GEMM  C[M,N] = A[M,K] * Bt[N,K]^T.  128x256 block tile, BK=64; each
// wave owns 64x128 (acc[4][8]) -> per ks-step 12 ds_read_b128 feed 32 MFMA
// (reads:MFMA 1:1, was 1.3:1 at 64x64).  XOR-source-swizzled 64-wide LDS
// rows (R6-proven). LDS 48 KB; __launch_bounds__(256,2) pins 2 blocks/CU.
// EPI 0 (QKV): cols <2048 -> qk buffer (width 2048); cols >=2048 are V ->
//   written pre-transposed to vt[bh][d][t] with packed 8B stores.
// EPI 1: outb = bf16(gelu(acc + bias[col])), width N.
// ---------------------------------------------------------------------------
template <int EPI>
__global__ __launch_bounds__(256, 2) void gemm_bt(const __hip_bfloat16* __restrict__ A,
                                                  const __hip_bfloat16* __restrict__ Bt,
                                                  __hip_bfloat16* __restrict__ outb,
                                                  __hip_bfloat16* __restrict__ vt,
                                                  const float* __restrict__ bias,
                                                  int M, int N, int K) {
    __shared__ __align__(16) __hip_bfloat16 As[128 * 64];  // 16 KB
    __shared__ __align__(16) __hip_bfloat16 Bs[256 * 64];  // 32 KB
    const int t = threadIdx.x;
    const int w = t >> 6, l = t & 63;
    const int quad = l >> 4, tl = l & 15;
    const int wr = w >> 1, wc = w & 1;
    const int m0 = blockIdx.y * 128, n0 = blockIdx.x * 256;

    floatx4 acc[4][8] = {};
    const int srow = t >> 3;   // 0..31
    const int scg  = t & 7;    // col group (8 groups of 8)

    for (int k0 = 0; k0 < K; k0 += 64) {
        __syncthreads();
        for (int p = 0; p < 4; ++p) {
            const int row = p * 32 + srow;
            async_copy16(A + (size_t)(m0 + row) * K + k0 + ((scg ^ (row & 7)) << 3),
                         As + p * 2048 + w * 512);
        }
        for (int p = 0; p < 8; ++p) {
            const int row = p * 32 + srow;
            async_copy16(Bt + (size_t)(n0 + row) * K + k0 + ((scg ^ (row & 7)) << 3),
                         Bs + p * 2048 + w * 512);
        }
        __syncthreads();

        for (int ks = 0; ks < 2; ++ks) {
            bf16x8 af[4], bfr[8];
            for (int mi = 0; mi < 4; ++mi) {
                const int r = wr * 64 + mi * 16 + tl;
                af[mi] = *(const bf16x8*)(As + r * 64 + (((ks * 4 + quad) ^ (r & 7)) << 3));
            }
            for (int ni = 0; ni < 8; ++ni) {
                const int r = wc * 128 + ni * 16 + tl;
                bfr[ni] = *(const bf16x8*)(Bs + r * 64 + (((ks * 4 + quad) ^ (r & 7)) << 3));
            }
            for (int mi = 0; mi < 4; ++mi)
                for (int ni = 0; ni < 8; ++ni)
                    acc[mi][ni] = mfma_bf16(af[mi], bfr[ni], acc[mi][ni]);
        }
    }

    const int rowBase = m0 + wr * 64 + quad * 4;
    const int colBase = n0 + wc * 128 + tl;
    if (EPI == 0 && n0 >= 2048) {
        // V region: write transposed vt[bh][d][t], 4 consecutive t packed (8B)
        for (int mi = 0; mi < 4; ++mi) {
            const int rb = rowBase + mi * 16;          // multiple of 4
            const int bb = rb >> 11, trow = rb & 2047;
            for (int ni = 0; ni < 8; ++ni) {
                const int c = colBase + ni * 16;
                const int hh = (c - 2048) >> 6, dd = (c - 2048) & 63;
                bf4 pk;
                for (int j = 0; j < 4; ++j) pk.x[j] = __float2bfloat16(acc[mi][ni][j]);
                *(bf4*)(vt + (((size_t)(bb * 16 + hh)) * 64 + dd) * TSEQ + trow) = pk;
            }
        }
    } else {
        for (int mi = 0; mi < 4; ++mi) {
            for (int ni = 0; ni < 8; ++ni) {
                const int c = colBase + ni * 16;
                for (int j = 0; j < 4; ++j) {
                    const int r = rowBase + mi * 16 + j;
                    float v = acc[mi][ni][j];
                    if (EPI == 1) {
                        v += bias[c];
                        v = 0.5f * v * (1.0f + erff(v * 0.70710678118654752f));
                        outb[(size_t)r * N + c] = __float2bfloat16(v);
                    } else {
                        outb[(size_t)r * QK_LD + c] = __float2bfloat16(v);
                    }
                }
            }
        }
    }
}

// ---------------------------------------------------------------------------
// bf16 GEMM, 128x64 tile, BK=128: 32 MFMA per barrier pair for the skinny-N
// (N=1024) GEMMs. fp32 epilogue: outf = resid + acc + bias[col].
// XOR-source-swizzled LDS; XCD-grouped block mapping.
// ---------------------------------------------------------------------------
__global__ __launch_bounds__(256) void gemm_bt_k128(const __hip_bfloat16* __restrict__ A,
                                                    const __hip_bfloat16* __restrict__ Bt,
                                                    float* __restrict__ outf,
                                                    const float* __restrict__ bias,
                                                    const float* __restrict__ resid,
                                                    int M, int N, int K) {
    __shared__ __align__(16) __hip_bfloat16 As[128 * 128];  // 32 KB
    __shared__ __align__(16) __hip_bfloat16 Bs[64 * 128];   // 16 KB
    const int t = threadIdx.x;
    const int w = t >> 6, l = t & 63;
    const int quad = l >> 4, tl = l & 15;
    const int id = blockIdx.x;
    const int xcd = id & 7, jb = id >> 3;
    const int n0 = (jb & 15) * 64;
    const int m0 = ((jb >> 4) * 8 + xcd) * 128;

    floatx4 acc[2][4] = {};
    const int srow = t >> 4;   // 0..15
    const int scg  = t & 15;   // col group

    for (int k0 = 0; k0 < K; k0 += 128) {
        __syncthreads();
        for (int p = 0; p < 8; ++p) {
            const int row = p * 16 + srow;
            async_copy16(A + (size_t)(m0 + row) * K + k0 + ((scg ^ (row & 7)) << 3),
                         As + p * 2048 + w * 512);
        }
        for (int p = 0; p < 4; ++p) {
            const int row = p * 16 + srow;
            async_copy16(Bt + (size_t)(n0 + row) * K + k0 + ((scg ^ (row & 7)) << 3),
                         Bs + p * 2048 + w * 512);
        }
        __syncthreads();

        for (int ks = 0; ks < 4; ++ks) {
            bf16x8 af[2], bfr[4];
            for (int mi = 0; mi < 2; ++mi) {
                const int r = w * 32 + mi * 16 + tl;
                af[mi] = *(const bf16x8*)(As + r * 128 + (((ks * 4 + quad) ^ (r & 7)) << 3));
            }
            for (int ni = 0; ni < 4; ++ni) {
                const int r = ni * 16 + tl;
                bfr[ni] = *(const bf16x8*)(Bs + r * 128 + (((ks * 4 + quad) ^ (r & 7)) << 3));
            }
            for (int mi = 0; mi < 2; ++mi)
                for (int ni = 0; ni < 4; ++ni)
                    acc[mi][ni] = mfma_bf16(af[mi], bfr[ni], acc[mi][ni]);
        }
    }

    const int rowBase = m0 + w * 32 + quad * 4;
    const int colBase = n0 + tl;
    for (int mi = 0; mi < 2; ++mi) {
        for (int ni = 0; ni < 4; ++ni) {
            const int c = colBase + ni * 16;
            for (int j = 0; j < 4; ++j) {
                const int r = rowBase + mi * 16 + j;
                const size_t idx = (size_t)r * N + c;
                outf[idx] = resid[idx] + acc[mi][ni][j] + bias[c];
            }
        }
    }
}

// ---------------------------------------------------------------------------
// Flash causal attention: ping-pong K/V LDS buffers (1 barrier per key-block)
// with register prefetch of the next block; pair scheduling (pq, 31-pq) for
// uniform 33 iters/workgroup; no-max softmax. All loops static.
// ---------------------------------------------------------------------------
#define KS_LD 72
#define VT_LD 72
#define PL_LD 72
__global__ __launch_bounds__(256) void attn_kernel(const __hip_bfloat16* __restrict__ qk,
                                                   const __hip_bfloat16* __restrict__ vt,
                                                   __hip_bfloat16* __restrict__ out) {
    __shared__ __align__(16) __hip_bfloat16 Ks[2][64 * KS_LD];
    __shared__ __align__(16) __hip_bfloat16 Vts[2][64 * VT_LD];
    __shared__ __align__(16) __hip_bfloat16 Pl[4][16 * PL_LD];
    const int t = threadIdx.x;
    const int w = t >> 6, l = t & 63;
    const int quad = l >> 4, tl = l & 15;
    const int id = blockIdx.x;                        // 0..511
    const int bh = ((id & 7) << 2) | ((id >> 3) & 3); // 0..31
    const int pq = id >> 5;                           // 0..15
    const int b = bh >> 4, h = bh & 15;
    const __hip_bfloat16* Qp  = qk + (size_t)b * TSEQ * QK_LD + h * HDIM;
    const __hip_bfloat16* Kp  = Qp + 1024;
    const __hip_bfloat16* Vtp = vt + (size_t)bh * HDIM * TSEQ;
    __hip_bfloat16* P = Pl[w];
    const float cscale = 0.125f * 1.4426950408889634f;  // K^-0.5 * log2(e)
    const int srow = t >> 3, sk8 = t & 7;

    for (int half = 0; half < 2; ++half) {
        const int qb = half ? (31 - pq) : pq;  // 64-row q-block
        const int qw = qb * 64 + w * 16;       // this wave's q-row base
        const int nb = qb + 1;

        const __hip_bfloat16* qrow = Qp + (size_t)(qw + tl) * QK_LD + quad * 8;
        const bf16x8 qf0 = *(const bf16x8*)qrow;
        const bf16x8 qf1 = *(const bf16x8*)(qrow + 32);
        floatx4 oacc[4] = {};
        float l_i[4] = {0.0f, 0.0f, 0.0f, 0.0f};
        const int myrow = quad * 4;

        __syncthreads();   // buf0 free (previous half done)
        // preload key-block 0 into buffer 0
        for (int i = 0; i < 2; ++i) {
            const int rr = i * 32 + srow;
            *(bf16x8*)(Ks[0]  + rr * KS_LD + sk8 * 8) =
                *(const bf16x8*)(Kp + (size_t)rr * QK_LD + sk8 * 8);
            *(bf16x8*)(Vts[0] + rr * VT_LD + sk8 * 8) =
                *(const bf16x8*)(Vtp + (size_t)rr * TSEQ + sk8 * 8);
        }
        __syncthreads();

        for (int it = 0; it < nb; ++it) {
            const int cb = it & 1;
            const bool pf = (it + 1 < nb);     // uniform across block
            bf16x8 krg[2], vrg[2];
            if (pf) {
                const int s0n = (it + 1) * 64;
                for (int i = 0; i < 2; ++i) {
                    const int rr = i * 32 + srow;
                    krg[i] = *(const bf16x8*)(Kp + (size_t)(s0n + rr) * QK_LD + sk8 * 8);
                    vrg[i] = *(const bf16x8*)(Vtp + (size_t)rr * TSEQ + s0n + sk8 * 8);
                }
            }

            // QK^T: 16 q-rows x 64 keys from buffer cb
            floatx4 sc[4];
            for (int ni = 0; ni < 4; ++ni) {
                const __hip_bfloat16* kr = Ks[cb] + (ni * 16 + tl) * KS_LD + quad * 8;
                floatx4 z = {0.0f, 0.0f, 0.0f, 0.0f};
                z = mfma_bf16(qf0, *(const bf16x8*)kr, z);
                sc[ni] = mfma_bf16(qf1, *(const bf16x8*)(kr + 32), z);
            }

            // no-max softmax; C-layout: q-row = quad*4+j, key = ni*16+tl
            const bool lastB = (it == nb - 1);
            for (int ni = 0; ni < 4; ++ni) {
                const int keyrel = ni * 16 + tl - w * 16;
                for (int j = 0; j < 4; ++j) {
                    float pv = exp2f(sc[ni][j] * cscale);
                    if (lastB && keyrel > myrow + j) pv = 0.0f;  // causal mask
                    l_i[j] += pv;
                    P[(myrow + j) * PL_LD + ni * 16 + tl] = __float2bfloat16(pv);
                }
            }
            __builtin_amdgcn_wave_barrier();

            // PV: P (A-layout) x V^T tiles from buffer cb
            for (int kc = 0; kc < 2; ++kc) {
                const bf16x8 pfr = *(const bf16x8*)(P + tl * PL_LD + kc * 32 + quad * 8);
                for (int ni = 0; ni < 4; ++ni) {
                    const bf16x8 vf = *(const bf16x8*)(Vts[cb] + (ni * 16 + tl) * VT_LD
                                                       + kc * 32 + quad * 8);
                    oacc[ni] = mfma_bf16(pfr, vf, oacc[ni]);
                }
            }

            if (pf) {   // publish next block into the other buffer
                for (int i = 0; i < 2; ++i) {
                    const int rr = i * 32 + srow;
                    *(bf16x8*)(Ks[cb ^ 1]  + rr * KS_LD + sk8 * 8) = krg[i];
                    *(bf16x8*)(Vts[cb ^ 1] + rr * VT_LD + sk8 * 8) = vrg[i];
                }
            }
            __syncthreads();   // single barrier per iteration
        }

        // deferred 16-lane l reduction, batched
        for (int d = 1; d < 16; d <<= 1) {
            float r0 = __shfl_xor(l_i[0], d), r1 = __shfl_xor(l_i[1], d);
            float r2 = __shfl_xor(l_i[2], d), r3 = __shfl_xor(l_i[3], d);
            l_i[0] += r0; l_i[1] += r1; l_i[2] += r2; l_i[3] += r3;
        }
        for (int j = 0; j < 4; ++j) {
            const float inv = 1.0f / l_i[j];
            const int rg = qw + quad * 4 + j;
            __hip_bfloat16* orow = out + ((size_t)b * TSEQ + rg) * DIM + h * HDIM;
            for (int ni = 0; ni < 4; ++ni)
                orow[ni * 16 + tl] = __float2bfloat16(oacc[ni][j] * inv);
        }
    }
}

// ---------------------------------------------------------------------------
extern "C" void kernel_launch(void* const* d_in, const int* in_sizes, int n_in,
                              void* d_out, int out_size, void* d_ws, size_t ws_size,
                              hipStream_t stream) {
    const float* x   = (const float*)d_in[0];
    const float* Wq  = (const float*)d_in[1];
    const float* Wk  = (const float*)d_in[2];
    const float* Wv  = (const float*)d_in[3];
    const float* Wo  = (const float*)d_in[4];
    const float* bo  = (const float*)d_in[5];
    const float* W1  = (const float*)d_in[6];
    const float* b1  = (const float*)d_in[7];
    const float* W2  = (const float*)d_in[8];
    const float* b2  = (const float*)d_in[9];
    const float* g1  = (const float*)d_in[10];
    const float* be1 = (const float*)d_in[11];
    const float* g2  = (const float*)d_in[12];
    const float* be2 = (const float*)d_in[13];
    float* out = (float*)d_out;

    size_t off = 0;
    char* wsb = (char*)d_ws;
    auto carve = [&](size_t bytes) {
        void* p = wsb + off;
        off += (bytes + 255) & ~(size_t)255;
        return p;
    };
    __hip_bfloat16* WqkvT = (__hip_bfloat16*)carve((size_t)3072 * 1024 * 2);
    __hip_bfloat16* WoT   = (__hip_bfloat16*)carve((size_t)1024 * 1024 * 2);
    __hip_bfloat16* W1T   = (__hip_bfloat16*)carve((size_t)4096 * 1024 * 2);
    __hip_bfloat16* W2T   = (__hip_bfloat16*)carve((size_t)1024 * 4096 * 2);
    __hip_bfloat16* h1    = (__hip_bfloat16*)carve((size_t)BT * DIM * 2);
    __hip_bfloat16* qkb   = (__hip_bfloat16*)carve((size_t)BT * QK_LD * 2);
    __hip_bfloat16* vtb   = (__hip_bfloat16*)carve((size_t)BT * DIM * 2);
    __hip_bfloat16* att   = (__hip_bfloat16*)carve((size_t)BT * DIM * 2);
    float*          x2    = (float*)carve((size_t)BT * DIM * 4);
    __hip_bfloat16* h2    = (__hip_bfloat16*)carve((size_t)BT * DIM * 2);
    __hip_bfloat16* ff1   = (__hip_bfloat16*)carve((size_t)BT * DFF * 2);

    // fused prep: LN1 + all weight transposes (one dispatch, 7168 blocks)
    prep_kernel<<<7168, 256, 0, stream>>>(x, g1, be1, Wq, Wk, Wv, Wo, W1, W2,
                                          h1, WqkvT, WoT, W1T, W2T);
    // fused QKV projection; V written pre-transposed into vtb
    gemm_bt<0><<<dim3(12, 32), 256, 0, stream>>>(h1, WqkvT, qkb, vtb, nullptr,
                                                 BT, 3072, DIM);
    // causal MHA
    attn_kernel<<<512, 256, 0, stream>>>(qkb, vtb, att);
    // x2 = x + att @ Wo + bo   (fp32)
    gemm_bt_k128<<<512, 256, 0, stream>>>(att, WoT, x2, bo, x, BT, DIM, DIM);
    // LN2
    ln_kernel<<<BT, 256, 0, stream>>>(x2, g2, be2, h2);
    // ff = gelu(h2 @ W1 + b1)  bf16 [4096,4096]
    gemm_bt<1><<<dim3(16, 32), 256, 0, stream>>>(h2, W1T, ff1, nullptr, b1,
                                                 BT, DFF, DIM);
    // out = x2 + ff @ W2 + b2  (fp32)
    gemm_bt_k128<<<512, 256, 0, stream>>>(ff1, W2T, out, b2, x2, BT, DIM, DFF);
}

// Round 15
// 335.701 us; speedup vs baseline: 2.7410x; 2.7410x over previous
//
#include <hip/hip_runtime.h>
#include <hip/hip_bf16.h>

// ---------------------------------------------------------------------------
// TransformerBlock: LN1 -> fused QKV GEMM (V written pre-transposed) ->
//   flash causal MHA -> Wo GEMM (+x) -> LN2 -> FF1 (+b1, GELU) -> FF2 (+x2)
// B=2, T=2048, D=1024, H=16, K=64, DFF=4096. fp32 I/O, bf16 MFMA internally.
// LESSONS (R4): register arrays only in fully-unrolled loops; stage via LDS.
// LESSON (R5/R6/R8/R11): more MFMA per barrier pair wins while VGPR fits.
// LESSON (R7): never trade occupancy for bank conflicts.
// LESSON (R10): XCD block-order swizzle = 0 byte FETCH change.
// LESSON (R12): attn was barrier-convoy bound -> ping-pong K/V LDS buffers.
// LESSON (R13): SQ_LDS_BANK_CONFLICT is structural for ds_read_b128 (exactly
// 4/read, swizzle-invariant); gemm_bt sits at its LDS/barrier plateau.
// LESSON (R14): acc[4][8] (32 floatx4) + __launch_bounds__(256,2) -> compiler
// SPILLED accs to scratch (VGPR_Count fell to 68 < acc footprint; 3.4 GB
// scratch traffic; 10x regression). Per-wave acc must stay <=16 floatx4.
// This file = R13 configuration (best measured: 340.26 us).
// ---------------------------------------------------------------------------

#define BT   4096   // B*T rows
#define DIM  1024
#define DFF  4096
#define TSEQ 2048
#define NHEAD 16
#define HDIM 64
#define QK_LD 2048   // fused Q|K buffer row width

typedef __attribute__((ext_vector_type(8))) short  bf16x8;
typedef __attribute__((ext_vector_type(4))) float  floatx4;
struct alignas(8) bf4 { __hip_bfloat16 x[4]; };

__device__ __forceinline__ void async_copy16(const __hip_bfloat16* g, __hip_bfloat16* l) {
    __builtin_amdgcn_global_load_lds(
        (const __attribute__((address_space(1))) void*)g,
        (__attribute__((address_space(3))) void*)l, 16, 0, 0);
}

__device__ __forceinline__ floatx4 mfma_bf16(bf16x8 a, bf16x8 b, floatx4 c) {
    return __builtin_amdgcn_mfma_f32_16x16x32_bf16(a, b, c, 0, 0, 0);
}

// ---------------------------------------------------------------------------
// LayerNorm: fp32 in -> bf16 out.  One block (256 thr) per row of 1024.
// ---------------------------------------------------------------------------
__device__ __forceinline__ void ln_body(const float* __restrict__ x,
                                        const float* __restrict__ g,
                                        const float* __restrict__ be,
                                        __hip_bfloat16* __restrict__ out,
                                        int row, float* red) {
    const int t = threadIdx.x;
    const float4 v = ((const float4*)(x + (size_t)row * DIM))[t];
    float s  = v.x + v.y + v.z + v.w;
    float ss = v.x * v.x + v.y * v.y + v.z * v.z + v.w * v.w;
    for (int d = 1; d < 64; d <<= 1) { s += __shfl_xor(s, d); ss += __shfl_xor(ss, d); }
    const int w = t >> 6;
    if ((t & 63) == 0) { red[w] = s; red[w + 4] = ss; }
    __syncthreads();
    s  = red[0] + red[1] + red[2] + red[3];
    ss = red[4] + red[5] + red[6] + red[7];
    const float mu = s * (1.0f / DIM);
    const float rstd = rsqrtf(ss * (1.0f / DIM) - mu * mu + 1e-5f);
    const float4 gv = ((const float4*)g)[t];
    const float4 bv = ((const float4*)be)[t];
    __hip_bfloat16* o = out + (size_t)row * DIM + t * 4;
    o[0] = __float2bfloat16((v.x - mu) * rstd * gv.x + bv.x);
    o[1] = __float2bfloat16((v.y - mu) * rstd * gv.y + bv.y);
    o[2] = __float2bfloat16((v.z - mu) * rstd * gv.z + bv.z);
    o[3] = __float2bfloat16((v.w - mu) * rstd * gv.w + bv.w);
}

__global__ __launch_bounds__(256) void ln_kernel(const float* __restrict__ x,
                                                 const float* __restrict__ g,
                                                 const float* __restrict__ be,
                                                 __hip_bfloat16* __restrict__ out) {
    __shared__ float red[8];
    ln_body(x, g, be, out, blockIdx.x, red);
}

// ---------------------------------------------------------------------------
// 64x64-tile transpose+cast body: dst[c][r] = (bf16)src[r][c]
// ---------------------------------------------------------------------------
__device__ __forceinline__ void tc_body(const float* __restrict__ src, int src_ld,
                                        __hip_bfloat16* __restrict__ dst, int dst_ld,
                                        int bx, int by, float* tile /*64*65*/) {
    const int r0 = bx * 64, c0 = by * 64;
    const int tr = threadIdx.x >> 6;   // 0..3
    const int tc = threadIdx.x & 63;   // 0..63
    for (int i = 0; i < 16; ++i) {
        const int r = i * 4 + tr;
        tile[r * 65 + tc] = src[(size_t)(r0 + r) * src_ld + c0 + tc];
    }
    __syncthreads();
    for (int i = 0; i < 16; ++i) {
        const int c = i * 4 + tr;
        dst[(size_t)(c0 + c) * dst_ld + r0 + tc] = __float2bfloat16(tile[tc * 65 + c]);
    }
}

// ---------------------------------------------------------------------------
// Fused prep: LN1 (4096 blocks) + transpose_qkv (768) + Wo^T (256) +
// W1^T (1024) + W2^T (1024) in one dispatch.  Grid = 7168.
// ---------------------------------------------------------------------------
__global__ __launch_bounds__(256) void prep_kernel(const float* __restrict__ x,
                                                   const float* __restrict__ g1,
                                                   const float* __restrict__ be1,
                                                   const float* __restrict__ Wq,
                                                   const float* __restrict__ Wk,
                                                   const float* __restrict__ Wv,
                                                   const float* __restrict__ Wo,
                                                   const float* __restrict__ W1,
                                                   const float* __restrict__ W2,
                                                   __hip_bfloat16* __restrict__ h1,
                                                   __hip_bfloat16* __restrict__ WqkvT,
                                                   __hip_bfloat16* __restrict__ WoT,
                                                   __hip_bfloat16* __restrict__ W1T,
                                                   __hip_bfloat16* __restrict__ W2T) {
    __shared__ __align__(16) float smemf[64 * 65];
    const int id = blockIdx.x;
    if (id < 4096) {
        ln_body(x, g1, be1, h1, id, smemf);
    } else if (id < 4096 + 768) {
        // transpose_qkv: Wq/Wk/Wv [H][D][64] -> WqkvT [3072][1024]
        const int i = id - 4096;
        const int bx = i & 15, hz = i >> 4;
        const int proj = hz >> 4, h = hz & 15;
        const float* W = (proj == 0 ? Wq : (proj == 1 ? Wk : Wv)) + (size_t)h * DIM * HDIM;
        const int r0 = bx * 64;
        const int tr = threadIdx.x >> 6, tc = threadIdx.x & 63;
        for (int i2 = 0; i2 < 16; ++i2) {
            const int r = i2 * 4 + tr;
            smemf[r * 65 + tc] = W[(size_t)(r0 + r) * HDIM + tc];
        }
        __syncthreads();
        for (int i2 = 0; i2 < 16; ++i2) {
            const int k = i2 * 4 + tr;
            WqkvT[(size_t)(proj * 1024 + h * 64 + k) * DIM + r0 + tc] =
                __float2bfloat16(smemf[tc * 65 + k]);
        }
    } else if (id < 4096 + 768 + 256) {
        const int i = id - (4096 + 768);
        tc_body(Wo, 1024, WoT, 1024, i & 15, i >> 4, smemf);
    } else if (id < 4096 + 768 + 256 + 1024) {
        const int i = id - (4096 + 768 + 256);
        tc_body(W1, 4096, W1T, 1024, i & 15, i >> 4, smemf);
    } else {
        const int i = id - (4096 + 768 + 256 + 1024);
        tc_body(W2, 1024, W2T, 4096, i & 63, i >> 6, smemf);
    }
}

// ---------------------------------------------------------------------------
// bf16 GEMM  C[M,N] = A[M,K] * Bt[N,K]^T.  128x128 tile, BK=128, unified
// XOR-source-swizzled LDS buffers. 64 MFMA per barrier pair, direct-store
// epilogue, acc[4][4] (16 floatx4 -- the R14 spill bound).
// EPI 0 (QKV): cols <2048 -> qk buffer (width 2048); cols >=2048 are V ->
//   written pre-transposed to vt[bh][d][t] with packed 8B stores.
// EPI 1: outb = bf16(gelu(acc + bias[col])), width N.
// ---------------------------------------------------------------------------
template <int EPI>
__global__ __launch_bounds__(256) void gemm_bt(const __hip_bfloat16* __restrict__ A,
                                               const __hip_bfloat16* __restrict__ Bt,
                                               __hip_bfloat16* __restrict__ outb,
                                               __hip_bfloat16* __restrict__ vt,
                                               const float* __restrict__ bias,
                                               int M, int N, int K) {
    __shared__ __align__(16) __hip_bfloat16 As[128 * 128];  // 32 KB
    __shared__ __align__(16) __hip_bfloat16 Bs[128 * 128];  // 32 KB
    const int t = threadIdx.x;
    const int w = t >> 6, l = t & 63;
    const int quad = l >> 4, tl = l & 15;
    const int wr = w >> 1, wc = w & 1;
    const int m0 = blockIdx.y * 128, n0 = blockIdx.x * 128;

    floatx4 acc[4][4] = {};
    const int srow = t >> 4;   // 0..15: row within each 16-row staging pass
    const int scg  = t & 15;   // col group (16 groups of 8 elements)

    for (int k0 = 0; k0 < K; k0 += 128) {
        __syncthreads();
        for (int p = 0; p < 8; ++p) {
            const int row = p * 16 + srow;
            const int off = (scg ^ (row & 7)) << 3;
            async_copy16(A  + (size_t)(m0 + row) * K + k0 + off, As + p * 2048 + w * 512);
            async_copy16(Bt + (size_t)(n0 + row) * K + k0 + off, Bs + p * 2048 + w * 512);
        }
        __syncthreads();

        for (int ks = 0; ks < 4; ++ks) {
            bf16x8 af[4], bfr[4];
            for (int mi = 0; mi < 4; ++mi) {
                const int r = wr * 64 + mi * 16 + tl;
                af[mi] = *(const bf16x8*)(As + r * 128 + (((ks * 4 + quad) ^ (r & 7)) << 3));
            }
            for (int ni = 0; ni < 4; ++ni) {
                const int r = wc * 64 + ni * 16 + tl;
                bfr[ni] = *(const bf16x8*)(Bs + r * 128 + (((ks * 4 + quad) ^ (r & 7)) << 3));
            }
            for (int mi = 0; mi < 4; ++mi)
                for (int ni = 0; ni < 4; ++ni)
                    acc[mi][ni] = mfma_bf16(af[mi], bfr[ni], acc[mi][ni]);
        }
    }

    const int rowBase = m0 + wr * 64 + quad * 4;
    const int colBase = n0 + wc * 64 + tl;
    if (EPI == 0 && n0 >= 2048) {
        // V region: write transposed vt[bh][d][t], 4 consecutive t packed (8B)
        for (int mi = 0; mi < 4; ++mi) {
            const int rb = rowBase + mi * 16;          // multiple of 4
            const int bb = rb >> 11, trow = rb & 2047;
            for (int ni = 0; ni < 4; ++ni) {
                const int c = colBase + ni * 16;
                const int hh = (c - 2048) >> 6, dd = (c - 2048) & 63;
                bf4 pk;
                for (int j = 0; j < 4; ++j) pk.x[j] = __float2bfloat16(acc[mi][ni][j]);
                *(bf4*)(vt + (((size_t)(bb * 16 + hh)) * 64 + dd) * TSEQ + trow) = pk;
            }
        }
    } else {
        for (int mi = 0; mi < 4; ++mi) {
            for (int ni = 0; ni < 4; ++ni) {
                const int c = colBase + ni * 16;
                for (int j = 0; j < 4; ++j) {
                    const int r = rowBase + mi * 16 + j;
                    float v = acc[mi][ni][j];
                    if (EPI == 1) {
                        v += bias[c];
                        v = 0.5f * v * (1.0f + erff(v * 0.70710678118654752f));
                        outb[(size_t)r * N + c] = __float2bfloat16(v);
                    } else {
                        outb[(size_t)r * QK_LD + c] = __float2bfloat16(v);
                    }
                }
            }
        }
    }
}

// ---------------------------------------------------------------------------
// bf16 GEMM, 128x64 tile, BK=128: 32 MFMA per barrier pair for the skinny-N
// (N=1024) GEMMs. fp32 epilogue: outf = resid + acc + bias[col].
// XOR-source-swizzled LDS; XCD-grouped block mapping.
// ---------------------------------------------------------------------------
__global__ __launch_bounds__(256) void gemm_bt_k128(const __hip_bfloat16* __restrict__ A,
                                                    const __hip_bfloat16* __restrict__ Bt,
                                                    float* __restrict__ outf,
                                                    const float* __restrict__ bias,
                                                    const float* __restrict__ resid,
                                                    int M, int N, int K) {
    __shared__ __align__(16) __hip_bfloat16 As[128 * 128];  // 32 KB
    __shared__ __align__(16) __hip_bfloat16 Bs[64 * 128];   // 16 KB
    const int t = threadIdx.x;
    const int w = t >> 6, l = t & 63;
    const int quad = l >> 4, tl = l & 15;
    const int id = blockIdx.x;
    const int xcd = id & 7, jb = id >> 3;
    const int n0 = (jb & 15) * 64;
    const int m0 = ((jb >> 4) * 8 + xcd) * 128;

    floatx4 acc[2][4] = {};
    const int srow = t >> 4;   // 0..15
    const int scg  = t & 15;   // col group

    for (int k0 = 0; k0 < K; k0 += 128) {
        __syncthreads();
        for (int p = 0; p < 8; ++p) {
            const int row = p * 16 + srow;
            async_copy16(A + (size_t)(m0 + row) * K + k0 + ((scg ^ (row & 7)) << 3),
                         As + p * 2048 + w * 512);
        }
        for (int p = 0; p < 4; ++p) {
            const int row = p * 16 + srow;
            async_copy16(Bt + (size_t)(n0 + row) * K + k0 + ((scg ^ (row & 7)) << 3),
                         Bs + p * 2048 + w * 512);
        }
        __syncthreads();

        for (int ks = 0; ks < 4; ++ks) {
            bf16x8 af[2], bfr[4];
            for (int mi = 0; mi < 2; ++mi) {
                const int r = w * 32 + mi * 16 + tl;
                af[mi] = *(const bf16x8*)(As + r * 128 + (((ks * 4 + quad) ^ (r & 7)) << 3));
            }
            for (int ni = 0; ni < 4; ++ni) {
                const int r = ni * 16 + tl;
                bfr[ni] = *(const bf16x8*)(Bs + r * 128 + (((ks * 4 + quad) ^ (r & 7)) << 3));
            }
            for (int mi = 0; mi < 2; ++mi)
                for (int ni = 0; ni < 4; ++ni)
                    acc[mi][ni] = mfma_bf16(af[mi], bfr[ni], acc[mi][ni]);
        }
    }

    const int rowBase = m0 + w * 32 + quad * 4;
    const int colBase = n0 + tl;
    for (int mi = 0; mi < 2; ++mi) {
        for (int ni = 0; ni < 4; ++ni) {
            const int c = colBase + ni * 16;
            for (int j = 0; j < 4; ++j) {
                const int r = rowBase + mi * 16 + j;
                const size_t idx = (size_t)r * N + c;
                outf[idx] = resid[idx] + acc[mi][ni][j] + bias[c];
            }
        }
    }
}

// ---------------------------------------------------------------------------
// Flash causal attention: ping-pong K/V LDS buffers (1 barrier per key-block)
// with register prefetch of the next block; pair scheduling (pq, 31-pq) for
// uniform 33 iters/workgroup; no-max softmax. All loops static.
// ---------------------------------------------------------------------------
#define KS_LD 72
#define VT_LD 72
#define PL_LD 72
__global__ __launch_bounds__(256) void attn_kernel(const __hip_bfloat16* __restrict__ qk,
                                                   const __hip_bfloat16* __restrict__ vt,
                                                   __hip_bfloat16* __restrict__ out) {
    __shared__ __align__(16) __hip_bfloat16 Ks[2][64 * KS_LD];
    __shared__ __align__(16) __hip_bfloat16 Vts[2][64 * VT_LD];
    __shared__ __align__(16) __hip_bfloat16 Pl[4][16 * PL_LD];
    const int t = threadIdx.x;
    const int w = t >> 6, l = t & 63;
    const int quad = l >> 4, tl = l & 15;
    const int id = blockIdx.x;                        // 0..511
    const int bh = ((id & 7) << 2) | ((id >> 3) & 3); // 0..31
    const int pq = id >> 5;                           // 0..15
    const int b = bh >> 4, h = bh & 15;
    const __hip_bfloat16* Qp  = qk + (size_t)b * TSEQ * QK_LD + h * HDIM;
    const __hip_bfloat16* Kp  = Qp + 1024;
    const __hip_bfloat16* Vtp = vt + (size_t)bh * HDIM * TSEQ;
    __hip_bfloat16* P = Pl[w];
    const float cscale = 0.125f * 1.4426950408889634f;  // K^-0.5 * log2(e)
    const int srow = t >> 3, sk8 = t & 7;

    for (int half = 0; half < 2; ++half) {
        const int qb = half ? (31 - pq) : pq;  // 64-row q-block
        const int qw = qb * 64 + w * 16;       // this wave's q-row base
        const int nb = qb + 1;

        const __hip_bfloat16* qrow = Qp + (size_t)(qw + tl) * QK_LD + quad * 8;
        const bf16x8 qf0 = *(const bf16x8*)qrow;
        const bf16x8 qf1 = *(const bf16x8*)(qrow + 32);
        floatx4 oacc[4] = {};
        float l_i[4] = {0.0f, 0.0f, 0.0f, 0.0f};
        const int myrow = quad * 4;

        __syncthreads();   // buf0 free (previous half done)
        // preload key-block 0 into buffer 0
        for (int i = 0; i < 2; ++i) {
            const int rr = i * 32 + srow;
            *(bf16x8*)(Ks[0]  + rr * KS_LD + sk8 * 8) =
                *(const bf16x8*)(Kp + (size_t)rr * QK_LD + sk8 * 8);
            *(bf16x8*)(Vts[0] + rr * VT_LD + sk8 * 8) =
                *(const bf16x8*)(Vtp + (size_t)rr * TSEQ + sk8 * 8);
        }
        __syncthreads();

        for (int it = 0; it < nb; ++it) {
            const int cb = it & 1;
            const bool pf = (it + 1 < nb);     // uniform across block
            bf16x8 krg[2], vrg[2];
            if (pf) {
                const int s0n = (it + 1) * 64;
                for (int i = 0; i < 2; ++i) {
                    const int rr = i * 32 + srow;
                    krg[i] = *(const bf16x8*)(Kp + (size_t)(s0n + rr) * QK_LD + sk8 * 8);
                    vrg[i] = *(const bf16x8*)(Vtp + (size_t)rr * TSEQ + s0n + sk8 * 8);
                }
            }

            // QK^T: 16 q-rows x 64 keys from buffer cb
            floatx4 sc[4];
            for (int ni = 0; ni < 4; ++ni) {
                const __hip_bfloat16* kr = Ks[cb] + (ni * 16 + tl) * KS_LD + quad * 8;
                floatx4 z = {0.0f, 0.0f, 0.0f, 0.0f};
                z = mfma_bf16(qf0, *(const bf16x8*)kr, z);
                sc[ni] = mfma_bf16(qf1, *(const bf16x8*)(kr + 32), z);
            }

            // no-max softmax; C-layout: q-row = quad*4+j, key = ni*16+tl
            const bool lastB = (it == nb - 1);
            for (int ni = 0; ni < 4; ++ni) {
                const int keyrel = ni * 16 + tl - w * 16;
                for (int j = 0; j < 4; ++j) {
                    float pv = exp2f(sc[ni][j] * cscale);
                    if (lastB && keyrel > myrow + j) pv = 0.0f;  // causal mask
                    l_i[j] += pv;
                    P[(myrow + j) * PL_LD + ni * 16 + tl] = __float2bfloat16(pv);
                }
            }
            __builtin_amdgcn_wave_barrier();

            // PV: P (A-layout) x V^T tiles from buffer cb
            for (int kc = 0; kc < 2; ++kc) {
                const bf16x8 pfr = *(const bf16x8*)(P + tl * PL_LD + kc * 32 + quad * 8);
                for (int ni = 0; ni < 4; ++ni) {
                    const bf16x8 vf = *(const bf16x8*)(Vts[cb] + (ni * 16 + tl) * VT_LD
                                                       + kc * 32 + quad * 8);
                    oacc[ni] = mfma_bf16(pfr, vf, oacc[ni]);
                }
            }

            if (pf) {   // publish next block into the other buffer
                for (int i = 0; i < 2; ++i) {
                    const int rr = i * 32 + srow;
                    *(bf16x8*)(Ks[cb ^ 1]  + rr * KS_LD + sk8 * 8) = krg[i];
                    *(bf16x8*)(Vts[cb ^ 1] + rr * VT_LD + sk8 * 8) = vrg[i];
                }
            }
            __syncthreads();   // single barrier per iteration
        }

        // deferred 16-lane l reduction, batched
        for (int d = 1; d < 16; d <<= 1) {
            float r0 = __shfl_xor(l_i[0], d), r1 = __shfl_xor(l_i[1], d);
            float r2 = __shfl_xor(l_i[2], d), r3 = __shfl_xor(l_i[3], d);
            l_i[0] += r0; l_i[1] += r1; l_i[2] += r2; l_i[3] += r3;
        }
        for (int j = 0; j < 4; ++j) {
            const float inv = 1.0f / l_i[j];
            const int rg = qw + quad * 4 + j;
            __hip_bfloat16* orow = out + ((size_t)b * TSEQ + rg) * DIM + h * HDIM;
            for (int ni = 0; ni < 4; ++ni)
                orow[ni * 16 + tl] = __float2bfloat16(oacc[ni][j] * inv);
        }
    }
}

// ---------------------------------------------------------------------------
extern "C" void kernel_launch(void* const* d_in, const int* in_sizes, int n_in,
                              void* d_out, int out_size, void* d_ws, size_t ws_size,
                              hipStream_t stream) {
    const float* x   = (const float*)d_in[0];
    const float* Wq  = (const float*)d_in[1];
    const float* Wk  = (const float*)d_in[2];
    const float* Wv  = (const float*)d_in[3];
    const float* Wo  = (const float*)d_in[4];
    const float* bo  = (const float*)d_in[5];
    const float* W1  = (const float*)d_in[6];
    const float* b1  = (const float*)d_in[7];
    const float* W2  = (const float*)d_in[8];
    const float* b2  = (const float*)d_in[9];
    const float* g1  = (const float*)d_in[10];
    const float* be1 = (const float*)d_in[11];
    const float* g2  = (const float*)d_in[12];
    const float* be2 = (const float*)d_in[13];
    float* out = (float*)d_out;

    size_t off = 0;
    char* wsb = (char*)d_ws;
    auto carve = [&](size_t bytes) {
        void* p = wsb + off;
        off += (bytes + 255) & ~(size_t)255;
        return p;
    };
    __hip_bfloat16* WqkvT = (__hip_bfloat16*)carve((size_t)3072 * 1024 * 2);
    __hip_bfloat16* WoT   = (__hip_bfloat16*)carve((size_t)1024 * 1024 * 2);
    __hip_bfloat16* W1T   = (__hip_bfloat16*)carve((size_t)4096 * 1024 * 2);
    __hip_bfloat16* W2T   = (__hip_bfloat16*)carve((size_t)1024 * 4096 * 2);
    __hip_bfloat16* h1    = (__hip_bfloat16*)carve((size_t)BT * DIM * 2);
    __hip_bfloat16* qkb   = (__hip_bfloat16*)carve((size_t)BT * QK_LD * 2);
    __hip_bfloat16* vtb   = (__hip_bfloat16*)carve((size_t)BT * DIM * 2);
    __hip_bfloat16* att   = (__hip_bfloat16*)carve((size_t)BT * DIM * 2);
    float*          x2    = (float*)carve((size_t)BT * DIM * 4);
    __hip_bfloat16* h2    = (__hip_bfloat16*)carve((size_t)BT * DIM * 2);
    __hip_bfloat16* ff1   = (__hip_bfloat16*)carve((size_t)BT * DFF * 2);

    // fused prep: LN1 + all weight transposes (one dispatch, 7168 blocks)
    prep_kernel<<<7168, 256, 0, stream>>>(x, g1, be1, Wq, Wk, Wv, Wo, W1, W2,
                                          h1, WqkvT, WoT, W1T, W2T);
    // fused QKV projection; V written pre-transposed into vtb
    gemm_bt<0><<<dim3(24, 32), 256, 0, stream>>>(h1, WqkvT, qkb, vtb, nullptr,
                                                 BT, 3072, DIM);
    // causal MHA
    attn_kernel<<<512, 256, 0, stream>>>(qkb, vtb, att);
    // x2 = x + att @ Wo + bo   (fp32)
    gemm_bt_k128<<<512, 256, 0, stream>>>(att, WoT, x2, bo, x, BT, DIM, DIM);
    // LN2
    ln_kernel<<<BT, 256, 0, stream>>>(x2, g2, be2, h2);
    // ff = gelu(h2 @ W1 + b1)  bf16 [4096,4096]
    gemm_bt<1><<<dim3(32, 32), 256, 0, stream>>>(h2, W1T, ff1, nullptr, b1,
                                                 BT, DFF, DIM);
    // out = x2 + ff @ W2 + b2  (fp32)
    gemm_bt_k128<<<512, 256, 0, stream>>>(ff1, W2T, out, b2, x2, BT, DIM, DFF);
}